// Round 1
// 1093.164 us; speedup vs baseline: 1.0470x; 1.0470x over previous
//
#include <hip/hip_runtime.h>
#include <hip/hip_bf16.h>

// Shapes
#define NB   128
#define CIN  1024
#define HW   256      // 16*16
#define DIN  2048
#define LL   512
#define DOUT 1024
#define NQ   16

#define SC   8        // d-split for k_scores (was 4)

typedef __attribute__((ext_vector_type(8))) short bf16x8;
typedef __attribute__((ext_vector_type(4))) float f32x4;

// K1: one wave per e; computes qT[e][qi] for all 16 qi.
// W_in row read exactly once (coalesced); query (128KB) stays cache-hot.
__global__ __launch_bounds__(256) void k_q(const float* __restrict__ query,
                                           const float* __restrict__ Win,
                                           float* __restrict__ qT) {
  int e    = blockIdx.x * 4 + (threadIdx.x >> 6);   // 2048 waves
  int lane = threadIdx.x & 63;
  const float* wr = Win + (size_t)e * DIN;
  float acc[16];
  #pragma unroll
  for (int qi = 0; qi < 16; ++qi) acc[qi] = 0.f;
  #pragma unroll 2
  for (int d = lane; d < DIN; d += 64) {
    float w = wr[d];
    #pragma unroll
    for (int qi = 0; qi < 16; ++qi) acc[qi] += w * query[qi * DIN + d];
  }
  #pragma unroll
  for (int qi = 0; qi < 16; ++qi) {
    float a = acc[qi];
    #pragma unroll
    for (int m = 32; m; m >>= 1) a += __shfl_xor(a, m);
    if (lane == 0) qT[e * 16 + qi] = a;
  }
}

// K1b: fill combined[:, 2048+e] = bf16(q[qi][e]); vectorized 16B stores.
__global__ __launch_bounds__(256) void k_qfill(const float* __restrict__ qT,
                                               __hip_bfloat16* __restrict__ comb) {
  int idx = blockIdx.x * 256 + threadIdx.x;          // 524288
  int m = idx >> 8, e0 = (idx & 255) * 8;
  int qi = m & 15;
  union { bf16x8 v; __hip_bfloat16 h[8]; } u;
  #pragma unroll
  for (int j = 0; j < 8; ++j) u.h[j] = __float2bfloat16(qT[(e0 + j) * 16 + qi]);
  *(bf16x8*)&comb[(size_t)m * (2 * DIN) + DIN + e0] = u.v;
}

// Kw: W_out fp32 -> bf16, 8 elems/thread.
__global__ __launch_bounds__(256) void k_wcast(const float* __restrict__ W,
                                               __hip_bfloat16* __restrict__ Wb) {
  int idx = blockIdx.x * 256 + threadIdx.x;          // 524288
  const float4* W4 = (const float4*)W;
  float4 a = W4[idx * 2], b = W4[idx * 2 + 1];
  union { bf16x8 v; __hip_bfloat16 h[8]; } u;
  u.h[0] = __float2bfloat16(a.x); u.h[1] = __float2bfloat16(a.y);
  u.h[2] = __float2bfloat16(a.z); u.h[3] = __float2bfloat16(a.w);
  u.h[4] = __float2bfloat16(b.x); u.h[5] = __float2bfloat16(b.y);
  u.h[6] = __float2bfloat16(b.z); u.h[7] = __float2bfloat16(b.w);
  *(bf16x8*)&Wb[(size_t)idx * 8] = u.v;
}

// K2: partial scores. grid (n=128, c=SC). lanes over l (float2). 4 blocks/CU.
__global__ __launch_bounds__(256) void k_scores(const float* __restrict__ ctx,
                                                const float* __restrict__ qT,
                                                float* __restrict__ part) {
  int n = blockIdx.x, c = blockIdx.y, t = threadIdx.x;
  const int DS = DIN / SC;                           // 256
  const float* cn  = ctx + (size_t)n * DIN * LL + (size_t)c * DS * LL;
  const float* qTc = qT + (size_t)c * DS * 16;
  float2 acc[16];
  #pragma unroll
  for (int qi = 0; qi < 16; ++qi) acc[qi] = make_float2(0.f, 0.f);
  #pragma unroll 4
  for (int d = 0; d < DS; ++d) {
    float2 v = *(const float2*)&cn[(size_t)d * LL + 2 * t];
    const float* qr = qTc + d * 16;
    #pragma unroll
    for (int qi = 0; qi < 16; ++qi) {
      acc[qi].x += qr[qi] * v.x;
      acc[qi].y += qr[qi] * v.y;
    }
  }
  float* po = part + (size_t)(c * NB + n) * 16 * LL;
  #pragma unroll
  for (int qi = 0; qi < 16; ++qi)
    *(float2*)&po[qi * LL + 2 * t] = acc[qi];
}

// K3: reduce partials + softmax over l. grid 2048 = (n, qi). Writes wT[n][l][qi].
__global__ __launch_bounds__(256) void k_softmax(const float* __restrict__ part,
                                                 float* __restrict__ wT) {
  int b = blockIdx.x, n = b >> 4, qi = b & 15, t = threadIdx.x;
  __shared__ float red[256];
  float sc0 = 0.f, sc1 = 0.f;
  #pragma unroll
  for (int c = 0; c < SC; ++c) {
    const float* p = part + ((size_t)(c * NB + n) * 16 + qi) * LL;
    sc0 += p[t];
    sc1 += p[t + 256];
  }
  red[t] = fmaxf(sc0, sc1);
  __syncthreads();
  for (int s = 128; s; s >>= 1) { if (t < s) red[t] = fmaxf(red[t], red[t + s]); __syncthreads(); }
  float M = red[0];
  __syncthreads();
  float e0 = expf(sc0 - M), e1 = expf(sc1 - M);
  red[t] = e0 + e1;
  __syncthreads();
  for (int s = 128; s; s >>= 1) { if (t < s) red[t] += red[t + s]; __syncthreads(); }
  float inv = 1.0f / red[0];
  wT[((size_t)n * LL + t) * 16 + qi]       = e0 * inv;
  wT[((size_t)n * LL + t + 256) * 16 + qi] = e1 * inv;
}

// K4: mix[n][qi][d] = sum_l wT[n][l][qi] * ctx[n][d][l]; writes bf16 into combined.
// T14 async-stage: issue next chunk's global loads into regs right after the
// barrier; compute phase overlaps with the 8 loads in flight; ds_write next iter.
__global__ __launch_bounds__(256) void k_mix(const float* __restrict__ ctx,
                                             const float* __restrict__ wT,
                                             __hip_bfloat16* __restrict__ comb) {
  int dt = blockIdx.x, n = blockIdx.y, t = threadIdx.x;
  int dbase = dt * 256;
  __shared__ float tile[256 * 33];
  const float* cn = ctx + (size_t)n * DIN * LL;
  const float* wn = wT + (size_t)n * LL * 16;
  const float* src0 = cn + (size_t)dbase * LL;
  float acc[16];
  #pragma unroll
  for (int qi = 0; qi < 16; ++qi) acc[qi] = 0.f;

  int lq = (t & 7) * 4;        // l-offset within chunk
  int row0 = t >> 3;           // 0..31; rows row0 + p*32

  float4 g[8];
  #pragma unroll
  for (int p = 0; p < 8; ++p)
    g[p] = *(const float4*)&src0[(size_t)(row0 + p * 32) * LL + lq];

  for (int ch = 0; ch < 16; ++ch) {
    __syncthreads();           // previous compute done; safe to overwrite tile
    #pragma unroll
    for (int p = 0; p < 8; ++p) {
      int row = row0 + p * 32;
      float* dst = &tile[row * 33 + lq];
      dst[0] = g[p].x; dst[1] = g[p].y; dst[2] = g[p].z; dst[3] = g[p].w;
    }
    __syncthreads();
    if (ch < 15) {             // prefetch next chunk; stays in flight during compute
      int l0n = (ch + 1) * 32;
      #pragma unroll
      for (int p = 0; p < 8; ++p)
        g[p] = *(const float4*)&src0[(size_t)(row0 + p * 32) * LL + l0n + lq];
    }
    int l0 = ch * 32;
    for (int l = 0; l < 32; ++l) {
      float v = tile[t * 33 + l];
      const float* wr = wn + (size_t)(l0 + l) * 16;   // wave-uniform -> s_load
      #pragma unroll
      for (int qi = 0; qi < 16; ++qi) acc[qi] += wr[qi] * v;
    }
  }
  #pragma unroll
  for (int qi = 0; qi < 16; ++qi)
    comb[(size_t)(n * 16 + qi) * (2 * DIN) + dbase + t] = __float2bfloat16(acc[qi]);
}

// K5: out_small = tanh(combined @ W_out^T) with fused nearest-upsample write.
// T14: next K-slice prefetched into regs before the MFMA phase.
__global__ __launch_bounds__(256) void k_gemm(const __hip_bfloat16* __restrict__ A,
                                              const __hip_bfloat16* __restrict__ B,
                                              float* __restrict__ out) {
  __shared__ short la[64 * 40];
  __shared__ short lb[64 * 40];
  int t = threadIdx.x, lane = t & 63, wid = t >> 6;
  int m0 = blockIdx.y * 64, o0 = blockIdx.x * 64;
  int wy = wid >> 1, wx = wid & 1;
  f32x4 acc[2][2] = {};
  int srow = t >> 2, sq = (t & 3) * 8;
  const short* As = (const short*)A;
  const short* Bs = (const short*)B;

  float4 ga = *(const float4*)&As[(size_t)(m0 + srow) * (2 * DIN) + sq];
  float4 gb = *(const float4*)&Bs[(size_t)(o0 + srow) * (2 * DIN) + sq];

  for (int kc = 0; kc < 2 * DIN; kc += 32) {
    __syncthreads();
    *(float4*)&la[srow * 40 + sq] = ga;
    *(float4*)&lb[srow * 40 + sq] = gb;
    __syncthreads();
    if (kc + 32 < 2 * DIN) {
      ga = *(const float4*)&As[(size_t)(m0 + srow) * (2 * DIN) + kc + 32 + sq];
      gb = *(const float4*)&Bs[(size_t)(o0 + srow) * (2 * DIN) + kc + 32 + sq];
    }
    int fr = lane & 15, fq = (lane >> 4) * 8;
    bf16x8 a0 = *(const bf16x8*)&la[(wy * 32 + fr) * 40 + fq];
    bf16x8 a1 = *(const bf16x8*)&la[(wy * 32 + 16 + fr) * 40 + fq];
    bf16x8 b0 = *(const bf16x8*)&lb[(wx * 32 + fr) * 40 + fq];
    bf16x8 b1 = *(const bf16x8*)&lb[(wx * 32 + 16 + fr) * 40 + fq];
    acc[0][0] = __builtin_amdgcn_mfma_f32_16x16x32_bf16(a0, b0, acc[0][0], 0, 0, 0);
    acc[0][1] = __builtin_amdgcn_mfma_f32_16x16x32_bf16(a0, b1, acc[0][1], 0, 0, 0);
    acc[1][0] = __builtin_amdgcn_mfma_f32_16x16x32_bf16(a1, b0, acc[1][0], 0, 0, 0);
    acc[1][1] = __builtin_amdgcn_mfma_f32_16x16x32_bf16(a1, b1, acc[1][1], 0, 0, 0);
  }

  int col = lane & 15, rbase = (lane >> 4) * 4;
  #pragma unroll
  for (int si = 0; si < 2; ++si)
    #pragma unroll
    for (int sj = 0; sj < 2; ++sj)
      #pragma unroll
      for (int r = 0; r < 4; ++r) {
        int m = m0 + wy * 32 + si * 16 + rbase + r;
        int o = o0 + wx * 32 + sj * 16 + col;
        float v = tanhf(acc[si][sj][r]);
        int n = m >> 4, qi = m & 15;
        float* op = out + (size_t)(n * 2048 + CIN + o) * HW
                        + ((qi >> 2) * 4) * 16 + (qi & 3) * 4;
        float4 vv = make_float4(v, v, v, v);
        *(float4*)&op[0]  = vv;
        *(float4*)&op[16] = vv;
        *(float4*)&op[32] = vv;
        *(float4*)&op[48] = vv;
      }
}

// K6: copy cat_tensor into channels [0,1024)
__global__ __launch_bounds__(256) void k_copy(const float* __restrict__ cat,
                                              float* __restrict__ out) {
  size_t idx = (size_t)blockIdx.x * 256 + threadIdx.x;  // float4 index, 8388608 total
  int n = (int)(idx >> 16);                              // 65536 float4 per n
  int rem = (int)(idx & 65535);
  const float4* c4 = (const float4*)cat;
  float4* o4 = (float4*)out;
  o4[(size_t)n * 131072 + rem] = c4[idx];
}

extern "C" void kernel_launch(void* const* d_in, const int* in_sizes, int n_in,
                              void* d_out, int out_size, void* d_ws, size_t ws_size,
                              hipStream_t stream) {
  const float* cat   = (const float*)d_in[0];
  const float* ctx   = (const float*)d_in[1];
  const float* query = (const float*)d_in[2];
  const float* W_in  = (const float*)d_in[3];
  const float* W_out = (const float*)d_in[4];
  float* out = (float*)d_out;

  // workspace layout (floats/bf16):
  // qT 32768 f | wT 1048576 f | part SC*128*16*512 f (=8388608, 32MB) | Wb 4M bf16 | comb 8M bf16
  float* qT   = (float*)d_ws;                          // 32768 f
  float* wT   = qT + 32768;                            // 1048576 f
  float* part = wT + 1048576;                          // 8388608 f
  __hip_bfloat16* Wb   = (__hip_bfloat16*)(part + 8388608);  // 4194304 bf16
  __hip_bfloat16* comb = Wb + 4194304;                        // 8388608 bf16

  k_q      <<<512, 256, 0, stream>>>(query, W_in, qT);
  k_wcast  <<<2048, 256, 0, stream>>>(W_out, Wb);
  k_qfill  <<<2048, 256, 0, stream>>>(qT, comb);
  k_scores <<<dim3(128, SC), 256, 0, stream>>>(ctx, qT, part);
  k_softmax<<<2048, 256, 0, stream>>>(part, wT);
  k_mix    <<<dim3(8, 128), 256, 0, stream>>>(ctx, wT, comb);
  k_gemm   <<<dim3(16, 32), 256, 0, stream>>>(comb, Wb, out);
  k_copy   <<<32768, 256, 0, stream>>>(cat, out);
}